// Round 1
// 5017.572 us; speedup vs baseline: 1.1656x; 1.1656x over previous
//
#include <hip/hip_runtime.h>
#include <cstdint>
#include <cstddef>

typedef __bf16 bf16;
typedef __bf16 bf16x8 __attribute__((ext_vector_type(8)));
typedef float f32x4 __attribute__((ext_vector_type(4)));

static __device__ __forceinline__ f32x4 mfma16(bf16x8 a, bf16x8 b, f32x4 c) {
  return __builtin_amdgcn_mfma_f32_16x16x32_bf16(a, b, c, 0, 0, 0);
}

// ---------------------------------------------------------------------------
// GRU step: one GEMM (512 x Ktot) @ (Ktot x 2880) with gate-permuted columns,
// fused GRU elementwise epilogue. Columns permuted: n' = g*96 + gate*32 + uu,
// orig col = gate*960 + g*32 + uu. K = [x-part (KXPAD) | h-part (960)].
// n-gate needs inn (x-part) separate -> accumulator checkpoint at k0==KXPAD.
//
// Tiling: block = 64 rows x 96 cols (one gate group). 4 waves = 2 row-halves
// x 2 unit-halves; wave = 2 m-frags x 3 gate-frags.
// K-loop: 64-k PAIR iterations (two 32-k LDS tiles per barrier), 4 tile
// slots (2 pair-buffers), 80-B pitch rows (2-way bank aliasing = free).
// Register prefetch: B staging AND A fragments both 2 pairs deep.
// Barrier is RAW: s_waitcnt lgkmcnt(0) + s_barrier (NOT __syncthreads, whose
// vmcnt(0) drain would serialize the global prefetch every iteration).
// Global loads therefore stay in flight across barriers (counted vmcnt).
// Grid x = 256 with swizzle: id = q*64 + s*8 + r, g = q*8+r, strip = s ->
// all 8 strips of group g share XCD (id%8 == g%8): B re-reads hit per-XCD L2.
// ---------------------------------------------------------------------------
struct StepArgs {
  const bf16* X;        // [512][ldx] bf16 input x
  const bf16* Hb;       // [512][960] bf16 prev hidden
  const bf16* Wt;       // [2880][Ktot] bf16, permuted cols
  const float* bA;      // [2880] r/z: bih+bhh ; n: bih
  const float* bB;      // [2880] r/z: 0       ; n: bhh
  const float* Hf_prev; // [512][960] f32 prev hidden
  float* Hf_next;       // [512][960] f32 new hidden
  bf16* Hb_next;        // [512][960] bf16 new hidden
  float* out_hidden;    // may be null; base = hid + t*1920 (+960 for layer 1)
  int ldx;
  int KXPAD;
  int Ktot;
  int _pad;
};

__global__ __launch_bounds__(256) void gru_step(StepArgs a0, StepArgs a1) {
  const StepArgs a = (blockIdx.z == 0) ? a0 : a1;
  const int id = blockIdx.x;
  const int gq = id >> 6, bm = (id >> 3) & 7, gr = id & 7;
  const int g = gq * 8 + gr;
  if (g >= 30) return;

  __shared__ bf16 ldsB[4 * 3840];  // 2 pair-buffers x 2 tiles (96x32, 80-B pitch)

  const int tid = threadIdx.x;
  const int wv = tid >> 6, lane = tid & 63, col = lane & 15, quad = lane >> 4;
  const int mh = wv & 1, uh = wv >> 1;
  const int Ktot = a.Ktot, KXPAD = a.KXPAD;
  const int nb = tid >> 3, cc = tid & 7;

  // B staging: thread covers rows nb, nb+32, nb+64; 8B chunk cc within 32-k row
  const bf16* Wb0 = a.Wt + ((size_t)g * 96 + nb) * Ktot + cc * 4;
  const size_t WrS = (size_t)32 * Ktot;
  char* ldsW = (char*)ldsB + nb * 80 + cc * 8;

  const int rowA = bm * 64 + mh * 32 + col;
  const bf16* Xrow = a.X + (size_t)rowA * a.ldx + quad * 8;
  const bf16* Hrow = a.Hb + (size_t)rowA * 960 + quad * 8 - KXPAD;
  const int ldx16 = 16 * a.ldx;

  // ---- epilogue operand preload: issue now, consume after the K-loop ----
  // (cannot sink below the first barrier: asm memory clobbers fence them)
  const int uu = uh * 16 + col;
  const int u = g * 32 + uu;
  const int gbase = g * 96;
  const float bAr = a.bA[gbase + uu];
  const float bAz = a.bA[gbase + 32 + uu];
  const float bAn = a.bA[gbase + 64 + uu];
  const float bBn = a.bB[gbase + 64 + uu];
  const int mb0 = bm * 64 + mh * 32 + quad * 4;
  float hold[2][4];
#pragma unroll
  for (int mf = 0; mf < 2; ++mf)
#pragma unroll
    for (int r = 0; r < 4; ++r)
      hold[mf][r] = a.Hf_prev[(size_t)(mb0 + mf * 16 + r) * 960 + u];

  const f32x4 z4 = {0.f, 0.f, 0.f, 0.f};
  f32x4 acc[2][3] = {{z4, z4, z4}, {z4, z4, z4}};
  f32x4 ck0 = z4, ck1 = z4;

  uint2 br0[6], br1[6];    // 2-pair-deep B staging (static indices -> VGPRs)
  bf16x8 ar0[4], ar1[4];   // 2-pair-deep A fragments

#define STAGEP(PH, K) do { int _ka = (K); int _kb = _ka + 32; if (_kb >= Ktot) _kb = 0; \
    br##PH[0] = *(const uint2*)(Wb0 + _ka); \
    br##PH[1] = *(const uint2*)(Wb0 + WrS + _ka); \
    br##PH[2] = *(const uint2*)(Wb0 + 2 * WrS + _ka); \
    br##PH[3] = *(const uint2*)(Wb0 + _kb); \
    br##PH[4] = *(const uint2*)(Wb0 + WrS + _kb); \
    br##PH[5] = *(const uint2*)(Wb0 + 2 * WrS + _kb); } while (0)

#define LOADA1(D0, D1, KK) do { int _k1 = (KK); \
    if (_k1 < KXPAD) { const bf16* _p = Xrow + _k1; D0 = *(const bf16x8*)_p; D1 = *(const bf16x8*)(_p + ldx16); } \
    else { const bf16* _p = Hrow + _k1; D0 = *(const bf16x8*)_p; D1 = *(const bf16x8*)(_p + 16 * 960); } } while (0)

#define LOADAP(PH, K) do { int _ka2 = (K); int _kb2 = _ka2 + 32; if (_kb2 >= Ktot) _kb2 = 0; \
    LOADA1(ar##PH[0], ar##PH[1], _ka2); LOADA1(ar##PH[2], ar##PH[3], _kb2); } while (0)

  const char* ldsRd = (char*)ldsB + (uh * 16 + col) * 80 + quad * 16;

  // lgkmcnt-only barrier: ds_writes (and prior ds_reads) drained; global
  // register loads stay outstanding across it.
#define BARRIER() do { \
    asm volatile("s_waitcnt lgkmcnt(0)" ::: "memory"); \
    __builtin_amdgcn_s_barrier(); \
    asm volatile("" ::: "memory"); } while (0)

#define GRU_PAIR(PH) do { \
    if (k0 == KXPAD) { ck0 = acc[0][2]; ck1 = acc[1][2]; } \
    char* _d = ldsW + bufoff; \
    *(uint2*)(_d)               = br##PH[0]; \
    *(uint2*)(_d + 2560)        = br##PH[1]; \
    *(uint2*)(_d + 5120)        = br##PH[2]; \
    *(uint2*)(_d + 7680)        = br##PH[3]; \
    *(uint2*)(_d + 7680 + 2560) = br##PH[4]; \
    *(uint2*)(_d + 7680 + 5120) = br##PH[5]; \
    bf16x8 am0 = ar##PH[0], am1 = ar##PH[1], am2 = ar##PH[2], am3 = ar##PH[3]; \
    BARRIER(); \
    { int _k2 = k0 + 128; if (_k2 >= Ktot) _k2 = 0; STAGEP(PH, _k2); LOADAP(PH, _k2); } \
    const char* _rp = ldsRd + bufoff; \
    _Pragma("unroll") \
    for (int gate = 0; gate < 3; ++gate) { \
      bf16x8 _bf = *(const bf16x8*)(_rp + gate * 2560); \
      acc[0][gate] = mfma16(am0, _bf, acc[0][gate]); \
      acc[1][gate] = mfma16(am1, _bf, acc[1][gate]); \
    } \
    if (k0 + 32 == KXPAD) { ck0 = acc[0][2]; ck1 = acc[1][2]; } \
    _Pragma("unroll") \
    for (int gate = 0; gate < 3; ++gate) { \
      bf16x8 _bf = *(const bf16x8*)(_rp + 7680 + gate * 2560); \
      acc[0][gate] = mfma16(am2, _bf, acc[0][gate]); \
      acc[1][gate] = mfma16(am3, _bf, acc[1][gate]); \
    } \
    k0 += 64; bufoff ^= 15360; \
  } while (0)

// tail: single 32-k tile (Ktot = 992 case), pair index = npair -> phase npair&1
#define TAILT(PH) do { \
    char* _d = ldsW + bufoff; \
    *(uint2*)(_d)        = br##PH[0]; \
    *(uint2*)(_d + 2560) = br##PH[1]; \
    *(uint2*)(_d + 5120) = br##PH[2]; \
    bf16x8 am0 = ar##PH[0], am1 = ar##PH[1]; \
    BARRIER(); \
    const char* _rp = ldsRd + bufoff; \
    _Pragma("unroll") \
    for (int gate = 0; gate < 3; ++gate) { \
      bf16x8 _bf = *(const bf16x8*)(_rp + gate * 2560); \
      acc[0][gate] = mfma16(am0, _bf, acc[0][gate]); \
      acc[1][gate] = mfma16(am1, _bf, acc[1][gate]); \
    } \
  } while (0)

  STAGEP(0, 0);
  STAGEP(1, 64);
  LOADAP(0, 0);
  LOADAP(1, 64);
  int k0 = 0, bufoff = 0;
  const int T32 = Ktot >> 5;
  const int npair = T32 >> 1;  // (992,32): 15 pairs + tail tile; (1920,960): 30 pairs
  for (int it = 0; it + 2 <= npair; it += 2) {
    GRU_PAIR(0);
    GRU_PAIR(1);
  }
  if (npair & 1) { GRU_PAIR(0); }
  if (T32 & 1) {
    if (k0 == KXPAD) { ck0 = acc[0][2]; ck1 = acc[1][2]; }
    if (npair & 1) TAILT(1); else TAILT(0);
  }

#undef GRU_PAIR
#undef TAILT
#undef BARRIER
#undef STAGEP
#undef LOADAP
#undef LOADA1

  // Epilogue: C/D layout col=lane&15 (unit), row=quad*4+reg (batch row).
#pragma unroll
  for (int mf = 0; mf < 2; ++mf) {
    f32x4 R = acc[mf][0], Z = acc[mf][1], Nf = acc[mf][2];
    f32x4 Nx = mf ? ck1 : ck0;
    const int mbase = mb0 + mf * 16;
#pragma unroll
    for (int r = 0; r < 4; ++r) {
      const int mm = mbase + r;
      float rg = 1.f / (1.f + __expf(-(R[r] + bAr)));
      float zg = 1.f / (1.f + __expf(-(Z[r] + bAz)));
      float inn = Nx[r] + bAn;
      float hn = (Nf[r] - Nx[r]) + bBn;
      float ng = tanhf(fmaf(rg, hn, inn));
      float hnew = fmaf(zg, hold[mf][r] - ng, ng);  // (1-z)*n + z*h
      a.Hf_next[(size_t)mm * 960 + u] = hnew;
      a.Hb_next[(size_t)mm * 960 + u] = (bf16)hnew;
      if (a.out_hidden) a.out_hidden[(size_t)mm * 92160 + u] = hnew;
    }
  }
}

// ---------------------------------------------------------------------------
// Final batched linear: outputs[b][t][n] = hid[b][t][960+k] . linW[n][k] + b[n]
// M = 512*48 rows, N = 32, K = 960.
// ---------------------------------------------------------------------------
__global__ __launch_bounds__(256) void final_linear(const float* __restrict__ hid,
                                                    const bf16* __restrict__ Wb,
                                                    const float* __restrict__ bias,
                                                    float* __restrict__ outp) {
  const int tid = threadIdx.x;
  const int wv = tid >> 6, lane = tid & 63, col = lane & 15, quad = lane >> 4;
  const int row = blockIdx.x * 64 + wv * 16 + col;  // 0..24575
  const int b = row / 48, t = row - b * 48;
  const float* arow = hid + (size_t)b * 92160 + (size_t)t * 1920 + 960 + quad * 8;
  const f32x4 z4 = {0.f, 0.f, 0.f, 0.f};
  f32x4 acc0 = z4, acc1 = z4;
  for (int k0 = 0; k0 < 960; k0 += 32) {
    f32x4 x0 = *(const f32x4*)(arow + k0);
    f32x4 x1 = *(const f32x4*)(arow + k0 + 4);
    bf16x8 af;
#pragma unroll
    for (int i = 0; i < 4; ++i) { af[i] = (bf16)x0[i]; af[4 + i] = (bf16)x1[i]; }
    bf16x8 b0 = *(const bf16x8*)(Wb + (size_t)col * 960 + k0 + quad * 8);
    bf16x8 b1 = *(const bf16x8*)(Wb + (size_t)(16 + col) * 960 + k0 + quad * 8);
    acc0 = mfma16(af, b0, acc0);
    acc1 = mfma16(af, b1, acc1);
  }
  const int mbase = blockIdx.x * 64 + wv * 16 + quad * 4;
#pragma unroll
  for (int r = 0; r < 4; ++r) {
    const int mm = mbase + r;
    const int b2 = mm / 48, t2 = mm - b2 * 48;
    float* o = outp + (size_t)b2 * 1536 + (size_t)t2 * 32;
    o[col] = acc0[r] + bias[col];
    o[16 + col] = acc1[r] + bias[16 + col];
  }
}

// ---------------------------------------------------------------------------
// Prep kernels (run each launch; weights arrive fp32, re-poisoned each call)
// ---------------------------------------------------------------------------
__global__ void prep_weight(const float* __restrict__ Wih, const float* __restrict__ Whh,
                            bf16* __restrict__ dst, int Kx, int KXPAD, int Ktot) {
  const int total = 2880 * Ktot;
  for (int e = blockIdx.x * blockDim.x + threadIdx.x; e < total; e += gridDim.x * blockDim.x) {
    int n = e / Ktot, k = e - n * Ktot;
    int g = n / 96, loc = n - g * 96, gate = loc >> 5, uu = loc & 31;
    int c = gate * 960 + g * 32 + uu;
    float v;
    if (k < KXPAD) v = (k < Kx) ? Wih[(size_t)c * Kx + k] : 0.f;
    else v = Whh[(size_t)c * 960 + (k - KXPAD)];
    dst[e] = (bf16)v;
  }
}

// dec layer0 for t>=1: x-part = Wih0 @ linW  (fold the feedback linear)
__global__ void prep_weight_dec0(const float* __restrict__ Wih, const float* __restrict__ Whh,
                                 const float* __restrict__ linW, bf16* __restrict__ dst) {
  const int total = 2880 * 1920;
  for (int e = blockIdx.x * blockDim.x + threadIdx.x; e < total; e += gridDim.x * blockDim.x) {
    int n = e / 1920, k = e - n * 1920;
    int g = n / 96, loc = n - g * 96, gate = loc >> 5, uu = loc & 31;
    int c = gate * 960 + g * 32 + uu;
    float v;
    if (k < 960) {
      float s = 0.f;
      for (int j = 0; j < 32; ++j) s = fmaf(Wih[(size_t)c * 32 + j], linW[(size_t)j * 960 + k], s);
      v = s;
    } else {
      v = Whh[(size_t)c * 960 + (k - 960)];
    }
    dst[e] = (bf16)v;
  }
}

__global__ void prep_bias(const float* __restrict__ bih, const float* __restrict__ bhh,
                          float* __restrict__ bA, float* __restrict__ bB) {
  int n = blockIdx.x * blockDim.x + threadIdx.x;
  if (n >= 2880) return;
  int g = n / 96, loc = n - g * 96, gate = loc >> 5, uu = loc & 31;
  int c = gate * 960 + g * 32 + uu;
  if (gate < 2) { bA[n] = bih[c] + bhh[c]; bB[n] = 0.f; }
  else          { bA[n] = bih[c];          bB[n] = bhh[c]; }
}

__global__ void prep_bias_dec0(const float* __restrict__ bih, const float* __restrict__ bhh,
                               const float* __restrict__ Wih, const float* __restrict__ linb,
                               float* __restrict__ bA, float* __restrict__ bB) {
  int n = blockIdx.x * blockDim.x + threadIdx.x;
  if (n >= 2880) return;
  int g = n / 96, loc = n - g * 96, gate = loc >> 5, uu = loc & 31;
  int c = gate * 960 + g * 32 + uu;
  float bi = bih[c];
  for (int j = 0; j < 32; ++j) bi = fmaf(Wih[(size_t)c * 32 + j], linb[j], bi);
  if (gate < 2) { bA[n] = bi + bhh[c]; bB[n] = 0.f; }
  else          { bA[n] = bi;          bB[n] = bhh[c]; }
}

__global__ void prep_xenc(const float* __restrict__ in_data, bf16* __restrict__ X) {
  int i = blockIdx.x * blockDim.x + threadIdx.x;
  if (i >= 64 * 512 * 32) return;
  int k = i & 31, m = (i >> 5) & 511, t = i >> 14;
  X[i] = (k < 16) ? (bf16)in_data[((size_t)m * 64 + t) * 16 + k] : (bf16)0.f;
}

__global__ void cvt_bf16(const float* __restrict__ s, bf16* __restrict__ d, int n) {
  int i = blockIdx.x * blockDim.x + threadIdx.x;
  if (i < n) d[i] = (bf16)s[i];
}

// ---------------------------------------------------------------------------
extern "C" void kernel_launch(void* const* d_in, const int* in_sizes, int n_in,
                              void* d_out, int out_size, void* d_ws, size_t ws_size,
                              hipStream_t stream) {
  (void)in_sizes; (void)n_in; (void)out_size; (void)ws_size;
  const float* in_data = (const float*)d_in[0];
  const float* last_loc = (const float*)d_in[1];
  const float* eWih0 = (const float*)d_in[3];
  const float* eWhh0 = (const float*)d_in[4];
  const float* ebih0 = (const float*)d_in[5];
  const float* ebhh0 = (const float*)d_in[6];
  const float* eWih1 = (const float*)d_in[7];
  const float* eWhh1 = (const float*)d_in[8];
  const float* ebih1 = (const float*)d_in[9];
  const float* ebhh1 = (const float*)d_in[10];
  const float* dWih0 = (const float*)d_in[11];
  const float* dWhh0 = (const float*)d_in[12];
  const float* dbih0 = (const float*)d_in[13];
  const float* dbhh0 = (const float*)d_in[14];
  const float* dWih1 = (const float*)d_in[15];
  const float* dWhh1 = (const float*)d_in[16];
  const float* dbih1 = (const float*)d_in[17];
  const float* dbhh1 = (const float*)d_in[18];
  const float* linW = (const float*)d_in[19];
  const float* linb = (const float*)d_in[20];
  float* outp = (float*)d_out;

  uint8_t* base = (uint8_t*)d_ws;
  size_t off = 0;
  auto alloc = [&](size_t bytes) -> void* {
    void* p = base + off;
    off += (bytes + 255) & ~(size_t)255;
    return p;
  };
  bf16* WtE0 = (bf16*)alloc(2880ull * 992 * 2);
  bf16* WtE1 = (bf16*)alloc(2880ull * 1920 * 2);
  bf16* WtD0a = (bf16*)alloc(2880ull * 992 * 2);
  bf16* WtD0 = (bf16*)alloc(2880ull * 1920 * 2);
  bf16* WtD1 = (bf16*)alloc(2880ull * 1920 * 2);
  bf16* linWb = (bf16*)alloc(32ull * 960 * 2);
  float* bA_e0 = (float*)alloc(2880 * 4); float* bB_e0 = (float*)alloc(2880 * 4);
  float* bA_e1 = (float*)alloc(2880 * 4); float* bB_e1 = (float*)alloc(2880 * 4);
  float* bA_d0a = (float*)alloc(2880 * 4); float* bB_d0a = (float*)alloc(2880 * 4);
  float* bA_d0 = (float*)alloc(2880 * 4); float* bB_d0 = (float*)alloc(2880 * 4);
  float* bA_d1 = (float*)alloc(2880 * 4); float* bB_d1 = (float*)alloc(2880 * 4);
  bf16* Xenc = (bf16*)alloc(64ull * 512 * 32 * 2);
  bf16* Xloc = (bf16*)alloc(512ull * 32 * 2);
  const int HS_ELEMS = 512 * 960;
  float* states = (float*)alloc((size_t)HS_ELEMS * (4 * 4 + 4 * 2));
  float* h0f[2] = {states, states + HS_ELEMS};
  float* h1f[2] = {states + 2 * HS_ELEMS, states + 3 * HS_ELEMS};
  bf16* bstates = (bf16*)(states + 4 * HS_ELEMS);
  bf16* h0b[2] = {bstates, bstates + HS_ELEMS};
  bf16* h1b[2] = {bstates + 2 * HS_ELEMS, bstates + 3 * HS_ELEMS};

  // ---- prep ----
  hipMemsetAsync(states, 0, (size_t)HS_ELEMS * (4 * 4 + 4 * 2), stream);
  prep_weight<<<4096, 256, 0, stream>>>(eWih0, eWhh0, WtE0, 16, 32, 992);
  prep_weight<<<8192, 256, 0, stream>>>(eWih1, eWhh1, WtE1, 960, 960, 1920);
  prep_weight<<<4096, 256, 0, stream>>>(dWih0, dWhh0, WtD0a, 32, 32, 992);
  prep_weight_dec0<<<8192, 256, 0, stream>>>(dWih0, dWhh0, linW, WtD0);
  prep_weight<<<8192, 256, 0, stream>>>(dWih1, dWhh1, WtD1, 960, 960, 1920);
  prep_bias<<<12, 256, 0, stream>>>(ebih0, ebhh0, bA_e0, bB_e0);
  prep_bias<<<12, 256, 0, stream>>>(ebih1, ebhh1, bA_e1, bB_e1);
  prep_bias<<<12, 256, 0, stream>>>(dbih0, dbhh0, bA_d0a, bB_d0a);
  prep_bias_dec0<<<12, 256, 0, stream>>>(dbih0, dbhh0, dWih0, linb, bA_d0, bB_d0);
  prep_bias<<<12, 256, 0, stream>>>(dbih1, dbhh1, bA_d1, bB_d1);
  prep_xenc<<<(64 * 512 * 32 + 255) / 256, 256, 0, stream>>>(in_data, Xenc);
  cvt_bf16<<<(512 * 32 + 255) / 256, 256, 0, stream>>>(last_loc, Xloc, 512 * 32);
  cvt_bf16<<<(32 * 960 + 255) / 256, 256, 0, stream>>>(linW, linWb, 32 * 960);

  auto step_args = [](const bf16* X, int ldx, const bf16* Hb, const bf16* Wt,
                      const float* bA, const float* bB, int KXPAD, int Ktot,
                      const float* Hfp, float* Hfn, bf16* Hbn, float* oh) {
    StepArgs s;
    s.X = X; s.ldx = ldx; s.Hb = Hb; s.Wt = Wt; s.bA = bA; s.bB = bB;
    s.KXPAD = KXPAD; s.Ktot = Ktot; s.Hf_prev = Hfp; s.Hf_next = Hfn;
    s.Hb_next = Hbn; s.out_hidden = oh; s._pad = 0;
    return s;
  };

  int p0 = 0, p1 = 0;
  // ---- encoder (L0 step t fused with L1 step t-1) ----
  {
    StepArgs s = step_args(Xenc, 32, h0b[p0], WtE0, bA_e0, bB_e0, 32, 992,
                           h0f[p0], h0f[1 - p0], h0b[1 - p0], nullptr);
    gru_step<<<dim3(256, 1, 1), 256, 0, stream>>>(s, s);
    p0 ^= 1;
  }
  for (int t = 1; t < 64; ++t) {
    StepArgs s0 = step_args(Xenc + (size_t)t * 512 * 32, 32, h0b[p0], WtE0, bA_e0, bB_e0, 32, 992,
                            h0f[p0], h0f[1 - p0], h0b[1 - p0], nullptr);
    StepArgs s1 = step_args(h0b[p0], 960, h1b[p1], WtE1, bA_e1, bB_e1, 960, 1920,
                            h1f[p1], h1f[1 - p1], h1b[1 - p1], nullptr);
    gru_step<<<dim3(256, 1, 2), 256, 0, stream>>>(s0, s1);
    p0 ^= 1; p1 ^= 1;
  }
  {
    StepArgs s1 = step_args(h0b[p0], 960, h1b[p1], WtE1, bA_e1, bB_e1, 960, 1920,
                            h1f[p1], h1f[1 - p1], h1b[1 - p1], nullptr);
    gru_step<<<dim3(256, 1, 1), 256, 0, stream>>>(s1, s1);
    p1 ^= 1;
  }
  // ---- decoder ----
  float* hid = outp + 786432;  // hidden_outputs base (512 x 48 x 1920)
  for (int t = 0; t < 48; ++t) {
    StepArgs s0;
    if (t == 0)
      s0 = step_args(Xloc, 32, h0b[p0], WtD0a, bA_d0a, bB_d0a, 32, 992,
                     h0f[p0], h0f[1 - p0], h0b[1 - p0], hid + (size_t)t * 1920);
    else
      s0 = step_args(h1b[p1], 960, h0b[p0], WtD0, bA_d0, bB_d0, 960, 1920,
                     h0f[p0], h0f[1 - p0], h0b[1 - p0], hid + (size_t)t * 1920);
    gru_step<<<dim3(256, 1, 1), 256, 0, stream>>>(s0, s0);
    p0 ^= 1;
    StepArgs s1 = step_args(h0b[p0], 960, h1b[p1], WtD1, bA_d1, bB_d1, 960, 1920,
                            h1f[p1], h1f[1 - p1], h1b[1 - p1], hid + (size_t)t * 1920 + 960);
    gru_step<<<dim3(256, 1, 1), 256, 0, stream>>>(s1, s1);
    p1 ^= 1;
  }
  // ---- all 48 outputs in one batched GEMM from stored h1 ----
  final_linear<<<384, 256, 0, stream>>>(hid, linWb, linb, outp);
}